// Round 21
// baseline (319.195 us; speedup 1.0000x reference)
//
#include <hip/hip_runtime.h>
#include <hip/hip_bf16.h>
#include <cstdint>

using bf16 = __hip_bfloat16;
typedef __bf16 bf16x8 __attribute__((ext_vector_type(8)));
typedef float f32x4 __attribute__((ext_vector_type(4)));

#define DEV static __device__ __forceinline__

DEV float toF(float x) { return x; }
DEV float toF(bf16 x) { return __bfloat162float(x); }

DEV float lo2f(unsigned int u) { return __builtin_bit_cast(float, u << 16); }
DEV float hi2f(unsigned int u) { return __builtin_bit_cast(float, u & 0xffff0000u); }
// round-half-up bf16 pair pack (5 ops; bias ~2^-9 rel — negligible here)
DEV unsigned int pkr(float lo, float hi) {
  return ((__builtin_bit_cast(unsigned int, lo) + 0x8000u) >> 16) |
         ((__builtin_bit_cast(unsigned int, hi) + 0x8000u) & 0xffff0000u);
}
DEV float fexp2(float x) {  // D = 2^x
  float r;
  asm("v_exp_f32 %0, %1" : "=v"(r) : "v"(x));
  return r;
}
DEV float frcp(float x) {
  float r;
  asm("v_rcp_f32 %0, %1" : "=v"(r) : "v"(x));
  return r;
}

// async global->LDS, 16B per lane. LDS dest = wave-uniform base + lane*16.
DEV void gload_lds16(const void* g, void* l) {
  __builtin_amdgcn_global_load_lds(
      (const __attribute__((address_space(1))) unsigned int*)g,
      (__attribute__((address_space(3))) unsigned int*)l, 16, 0, 0);
}

// ---- GEMM core v6: 256x128 tile, BK=64, 4 waves (2x2, 128x64/wave).
// Same verified single-buffered schedule as v3 (R18/R19 pipelining measured
// slower), but 2x FLOP per barrier-pair: 64 MFMA/wave/K-step vs 32, staging
// 12 vmem vs 8. Source-side XOR swizzle (chunk ^= row&7) keeps ds_read 2-way.
#define GEMM_CORE256(A_, lda_, B_, ldb_)                                       \
  f32x4 acc[8][4] = {};                                                        \
  {                                                                            \
    const int wave = tid >> 6, lane = tid & 63;                                \
    const int wm = (wave >> 1) * 128, wn = (wave & 1) * 64;                    \
    const int lrow = lane & 15;                                                \
    const int g = lane >> 4;                                                   \
    const int xk = lrow & 7;                                                   \
    for (int k0 = 0; k0 < 1024; k0 += 64) {                                    \
      _Pragma("unroll") for (int r = 0; r < 8; ++r) {                          \
        int c = r * 256 + tid;                                                 \
        int row = c >> 3, sub = c & 7;                                         \
        gload_lds16(A_ + (long long)(m0 + row) * lda_ + k0 +                   \
                        ((sub ^ (row & 7)) << 3),                              \
                    (void*)(ldsA + (r * 256 + wave * 64) * 8));                \
      }                                                                        \
      _Pragma("unroll") for (int r = 0; r < 4; ++r) {                          \
        int c = r * 256 + tid;                                                 \
        int row = c >> 3, sub = c & 7;                                         \
        gload_lds16(B_ + (long long)(n0 + row) * ldb_ + k0 +                   \
                        ((sub ^ (row & 7)) << 3),                              \
                    (void*)(ldsB + (r * 256 + wave * 64) * 8));                \
      }                                                                        \
      __syncthreads();                                                         \
      _Pragma("unroll") for (int kc = 0; kc < 2; ++kc) {                       \
        bf16x8 af[8], bfr[4];                                                  \
        _Pragma("unroll") for (int i = 0; i < 8; ++i)                          \
            af[i] = *(const bf16x8*)&ldsA[(wm + i * 16 + lrow) * 64 +          \
                                          (((kc * 4 + g) ^ xk) << 3)];         \
        _Pragma("unroll") for (int j = 0; j < 4; ++j)                          \
            bfr[j] = *(const bf16x8*)&ldsB[(wn + j * 16 + lrow) * 64 +         \
                                           (((kc * 4 + g) ^ xk) << 3)];        \
        _Pragma("unroll") for (int i = 0; i < 8; ++i)                          \
            _Pragma("unroll") for (int j = 0; j < 4; ++j)                      \
                acc[i][j] = __builtin_amdgcn_mfma_f32_16x16x32_bf16(           \
                    af[i], bfr[j], acc[i][j], 0, 0, 0);                        \
      }                                                                        \
      __syncthreads();                                                         \
    }                                                                          \
  }

// ---- GEMM core v3: 128x128 tile, BK=64 (unchanged, used by gemm_out) ----
#define GEMM_CORE128(A_, lda_, B_, ldb_)                                       \
  f32x4 acc[4][4] = {};                                                        \
  {                                                                            \
    const int wave = tid >> 6, lane = tid & 63;                                \
    const int wm = (wave >> 1) * 64, wn = (wave & 1) * 64;                     \
    const int lrow = lane & 15;                                                \
    const int g = lane >> 4;                                                   \
    const int xk = lrow & 7;                                                   \
    for (int k0 = 0; k0 < 1024; k0 += 64) {                                    \
      _Pragma("unroll") for (int r = 0; r < 4; ++r) {                          \
        int c = r * 256 + tid;                                                 \
        int row = c >> 3, sub = c & 7;                                         \
        gload_lds16(A_ + (long long)(m0 + row) * lda_ + k0 +                   \
                        ((sub ^ (row & 7)) << 3),                              \
                    (void*)(ldsA + (r * 256 + wave * 64) * 8));                \
      }                                                                        \
      _Pragma("unroll") for (int r = 0; r < 4; ++r) {                          \
        int c = r * 256 + tid;                                                 \
        int row = c >> 3, sub = c & 7;                                         \
        gload_lds16(B_ + (long long)(n0 + row) * ldb_ + k0 +                   \
                        ((sub ^ (row & 7)) << 3),                              \
                    (void*)(ldsB + (r * 256 + wave * 64) * 8));                \
      }                                                                        \
      __syncthreads();                                                         \
      _Pragma("unroll") for (int kc = 0; kc < 2; ++kc) {                       \
        bf16x8 af[4], bfr[4];                                                  \
        _Pragma("unroll") for (int i = 0; i < 4; ++i)                          \
            af[i] = *(const bf16x8*)&ldsA[(wm + i * 16 + lrow) * 64 +          \
                                          (((kc * 4 + g) ^ xk) << 3)];         \
        _Pragma("unroll") for (int j = 0; j < 4; ++j)                          \
            bfr[j] = *(const bf16x8*)&ldsB[(wn + j * 16 + lrow) * 64 +         \
                                           (((kc * 4 + g) ^ xk) << 3)];        \
        _Pragma("unroll") for (int i = 0; i < 4; ++i)                          \
            _Pragma("unroll") for (int j = 0; j < 4; ++j)                      \
                acc[i][j] = __builtin_amdgcn_mfma_f32_16x16x32_bf16(           \
                    af[i], bfr[j], acc[i][j], 0, 0, 0);                        \
      }                                                                        \
      __syncthreads();                                                         \
    }                                                                          \
  }

// Merged Q/K/V projection GEMMs: 768 blocks (256x128 tiles); which = bid>>8.
// which 0: qp = (Wq.q + bq)*log2e/8; 1: kph head-split = (kT.Wk^T + bk);
// 2: vptc chunk-split = (Wv.v + bv).
__launch_bounds__(256, 2)
__global__ void proj3(const bf16* __restrict__ Wq, const bf16* __restrict__ qT,
                      bf16* __restrict__ qp, const float* __restrict__ bq,
                      const bf16* __restrict__ kT, const bf16* __restrict__ Wk,
                      bf16* __restrict__ kph, const float* __restrict__ bk,
                      const bf16* __restrict__ Wv, const bf16* __restrict__ vT,
                      bf16* __restrict__ vptc, const float* __restrict__ bv) {
  __shared__ bf16 ldsA[256 * 64];
  __shared__ bf16 ldsB[128 * 64];
  const int tid = threadIdx.x;
  const int bid = blockIdx.x;
  const int which = bid >> 8, r0b = bid & 255;
  const long long z = r0b & 7;
  const int t = r0b >> 3;  // 0..31: 4 m-tiles x 8 n-tiles
  const int m0 = (t >> 3) * 256, n0 = (t & 7) * 128;
  const long long M1 = 1048576;

  const bf16* A;
  const bf16* B;
  const float* bias;
  bf16* C;
  float alpha;
  if (which == 0) {
    A = Wq; B = qT + z * M1; bias = bq; C = qp + z * M1; alpha = 0.18033688f;
  } else if (which == 1) {
    A = kT + z * M1; B = Wk; bias = bk; C = kph + z * M1; alpha = 1.0f;
  } else {
    A = Wv; B = vT + z * M1; bias = bv; C = vptc + z * M1; alpha = 1.0f;
  }

  GEMM_CORE256(A, 1024, B, 1024)

  const int wave = tid >> 6, lane = tid & 63;
  const int wm = (wave >> 1) * 128, wn = (wave & 1) * 64;
  const int lrow = lane & 15;
  const int r4 = (lane >> 4) * 4;
#pragma unroll
  for (int i = 0; i < 8; ++i) {
#pragma unroll
    for (int j = 0; j < 4; ++j) {
#pragma unroll
      for (int r = 0; r < 4; ++r) {
        int grow = m0 + wm + i * 16 + r4 + r;
        int gcol = n0 + wn + j * 16 + lrow;
        float vv = acc[i][j][r];
        if (which == 0) {
          vv = (vv + bias[grow]) * alpha;
          C[(long long)grow * 1024 + gcol] = __float2bfloat16(vv);
        } else if (which == 1) {
          vv += bias[gcol];
          long long idx = ((long long)(gcol >> 6) << 16) + grow * 64 + (gcol & 63);
          C[idx] = __float2bfloat16(vv);
        } else {
          vv += bias[grow];
          int mm = ((grow & 63) << 4) | (gcol >> 6);
          long long idx = ((long long)(grow >> 6) << 16) + ((mm >> 5) << 11) +
                          ((gcol & 63) << 5) + (mm & 31);
          C[idx] = __float2bfloat16(vv);
        }
      }
    }
  }
}

// Final projection: out = Wo . aoutT^T + bo, f32 out. 512 blocks, 128x128.
__launch_bounds__(256, 4)
__global__ void gemm_out(const bf16* __restrict__ Wo, const bf16* __restrict__ aoutT,
                         float* __restrict__ out, const float* __restrict__ bo) {
  __shared__ bf16 ldsA[128 * 64];
  __shared__ bf16 ldsB[128 * 64];
  const int tid = threadIdx.x;
  const int bid = blockIdx.x;
  const long long z = bid & 7;
  const int t = bid >> 3;
  const int m0 = (t >> 3) * 128, n0 = (t & 7) * 128;
  const long long M1 = 1048576;
  const bf16* A = Wo;
  const bf16* B = aoutT + z * M1;
  float* C = out + z * M1;

  GEMM_CORE128(A, 1024, B, 1024)

  const int wave = tid >> 6, lane = tid & 63;
  const int wm = (wave >> 1) * 64, wn = (wave & 1) * 64;
  const int lrow = lane & 15;
  const int r4 = (lane >> 4) * 4;
#pragma unroll
  for (int i = 0; i < 4; ++i)
#pragma unroll
    for (int j = 0; j < 4; ++j)
#pragma unroll
      for (int r = 0; r < 4; ++r) {
        int grow = m0 + wm + i * 16 + r4 + r;
        int gcol = n0 + wn + j * 16 + lrow;
        C[(long long)grow * 1024 + gcol] = acc[i][j][r] + bo[grow];
      }
}

// QK^T for one 64-wide mm' chunk of the wave's own head, S -> SPn (bf16 pairs)
#define QK_CHUNK(itv, SPn)                                                     \
  {                                                                            \
    const int mm0 = (itv) * 64;                                                \
    _Pragma("unroll") for (int mmf = 0; mmf < 4; ++mmf) {                      \
      const bf16* kr = Kb + (size_t)(mm0 + mmf * 16 + l15) * 64 + g * 8;       \
      bf16x8 k0 = *(const bf16x8*)kr;                                          \
      bf16x8 k1 = *(const bf16x8*)(kr + 32);                                   \
      f32x4 sa = {}, sb = {};                                                  \
      __builtin_amdgcn_s_setprio(1);                                           \
      sa = __builtin_amdgcn_mfma_f32_16x16x32_bf16(k0, qf[0][0], sa, 0, 0, 0); \
      sa = __builtin_amdgcn_mfma_f32_16x16x32_bf16(k1, qf[0][1], sa, 0, 0, 0); \
      sb = __builtin_amdgcn_mfma_f32_16x16x32_bf16(k0, qf[1][0], sb, 0, 0, 0); \
      sb = __builtin_amdgcn_mfma_f32_16x16x32_bf16(k1, qf[1][1], sb, 0, 0, 0); \
      __builtin_amdgcn_s_setprio(0);                                           \
      uint2 ua, ub;                                                            \
      ua.x = pkr(sa[0], sa[1]);                                                \
      ua.y = pkr(sa[2], sa[3]);                                                \
      ub.x = pkr(sb[0], sb[1]);                                                \
      ub.y = pkr(sb[2], sb[3]);                                                \
      *(uint2*)&(SPn)[hrow + l15 * 35 + mmf * 8 + g * 2] = ua;                 \
      *(uint2*)&(SPn)[hrow + (16 + l15) * 35 + mmf * 8 + g * 2] = ub;          \
    }                                                                          \
  }

// Fused attn, PIPELINED: 16 waves (=heads), 32-row m-tile, mm-chunk 64,
// double-buffered SP (2 x [16][32][35] u32 = 140KB). Per iter:
// {QK(it+1)->SPnext || softmax(it) on SPcur} -> barrier -> PV(it) (no trailing
// barrier: QK/PV touch only own-head rows; softmax works the other buffer).
// qp holds Q*(log2e/8) -> softmax = raw v_exp_f32, NO max-subtraction
// (scores bounded: std 0.41, |S|max ~2.4 -> exp<=11, f32-safe).
__launch_bounds__(1024, 4)
__global__ void fused_attn(const bf16* __restrict__ qp,
                           const bf16* __restrict__ kph,
                           const bf16* __restrict__ vptc,
                           bf16* __restrict__ aout) {
  __shared__ unsigned int SP[2][16 * 32 * 35];  // 2 x 70KB
  const int bid = blockIdx.x;
  const int bb = bid & 7, mt = bid >> 3;  // batch -> XCD
  const int tid = threadIdx.x;
  const int w = tid >> 6, lane = tid & 63;  // wave = head
  const int l15 = lane & 15, g = lane >> 4;

  const bf16* Qb = qp + ((size_t)bb << 20);
  const bf16* Kb = kph + ((size_t)bb << 20) + ((size_t)w << 16);
  const bf16* Vb = vptc + ((size_t)bb << 20) + ((size_t)w << 16);
  bf16* Ob = aout + ((size_t)bb << 20);

  // hoist this wave's head's Q fragments: 2 m-frags x 2 k-chunks (16 VGPRs)
  bf16x8 qf[2][2];
#pragma unroll
  for (int mf = 0; mf < 2; ++mf)
#pragma unroll
    for (int kc = 0; kc < 2; ++kc)
      qf[mf][kc] = *(const bf16x8*)(Qb + ((size_t)w << 16) +
                                    (mt * 32 + mf * 16 + l15) * 64 + kc * 32 + g * 8);

  f32x4 oacc[2][4] = {};
  const unsigned int hrow = w * 1120;  // own head's LDS base (u32), 32*35
  const int smbase = (tid >> 5) * 35 + (tid & 31);  // 1 softmax slot/thread

  QK_CHUNK(0, SP[0])
  __syncthreads();

  for (int it = 0; it < 16; ++it) {
    unsigned int* SPc = SP[it & 1];
    // ---- QK(it+1) into the other buffer (own head rows only) ----
    if (it < 15) QK_CHUNK(it + 1, SP[(it + 1) & 1])
    // ---- softmax(it) over 16 heads on SPc: single pass, exp2 domain ----
    {
      float el[16], eh[16];
#pragma unroll
      for (int h = 0; h < 16; ++h) {
        unsigned int u = SPc[h * 1120 + smbase];
        el[h] = fexp2(lo2f(u));
        eh[h] = fexp2(hi2f(u));
      }
      float sl = (((el[0] + el[1]) + (el[2] + el[3])) + ((el[4] + el[5]) + (el[6] + el[7]))) +
                 (((el[8] + el[9]) + (el[10] + el[11])) + ((el[12] + el[13]) + (el[14] + el[15])));
      float sh = (((eh[0] + eh[1]) + (eh[2] + eh[3])) + ((eh[4] + eh[5]) + (eh[6] + eh[7]))) +
                 (((eh[8] + eh[9]) + (eh[10] + eh[11])) + ((eh[12] + eh[13]) + (eh[14] + eh[15])));
      float il = frcp(sl), ih = frcp(sh);
#pragma unroll
      for (int h = 0; h < 16; ++h)
        SPc[h * 1120 + smbase] = pkr(el[h] * il, eh[h] * ih);
    }
    __syncthreads();
    // ---- PV(it) for own head over the 64 mm' just normalized ----
#pragma unroll
    for (int c = 0; c < 2; ++c) {
      uint4 pa0 = *(const uint4*)&SPc[hrow + l15 * 35 + c * 16 + g * 4];
      uint4 pa1 = *(const uint4*)&SPc[hrow + (16 + l15) * 35 + c * 16 + g * 4];
      bf16x8 p0 = __builtin_bit_cast(bf16x8, pa0);
      bf16x8 p1 = __builtin_bit_cast(bf16x8, pa1);
      const bf16* vb = Vb + ((it * 2 + c) << 11) + g * 8;
      __builtin_amdgcn_s_setprio(1);
#pragma unroll
      for (int dj = 0; dj < 4; ++dj) {
        bf16x8 vf = *(const bf16x8*)(vb + (dj * 16 + l15) * 32);
        oacc[0][dj] = __builtin_amdgcn_mfma_f32_16x16x32_bf16(p0, vf, oacc[0][dj], 0, 0, 0);
        oacc[1][dj] = __builtin_amdgcn_mfma_f32_16x16x32_bf16(p1, vf, oacc[1][dj], 0, 0, 0);
      }
      __builtin_amdgcn_s_setprio(0);
    }
    // no trailing barrier: QK(it+2) writes own-head rows of SPc; other waves'
    // PV(it) reads are also own-head rows (disjoint); softmax(it+1) reads the
    // OTHER buffer, whose writes were sealed by the post-softmax barrier.
  }
  // ---- write out flat (h, m, dt) concat layout ----
#pragma unroll
  for (int mf = 0; mf < 2; ++mf)
#pragma unroll
    for (int dj = 0; dj < 4; ++dj)
#pragma unroll
      for (int r = 0; r < 4; ++r)
        Ob[((size_t)w << 16) + (size_t)(mt * 32 + mf * 16 + g * 4 + r) * 64 +
           dj * 16 + l15] = __float2bfloat16(oacc[mf][dj][r]);
}

// out[c][r] = (bf16) in[r][c]
template <typename TIN>
__global__ void transpose_tile(const TIN* __restrict__ in, bf16* __restrict__ out,
                               int R, int C, long long sIn, long long sOut) {
  __shared__ float t[32][33];
  const long long z = blockIdx.z;
  in += z * sIn;
  out += z * sOut;
  const int r0 = blockIdx.y * 32, c0 = blockIdx.x * 32;
  const int tx = threadIdx.x, ty = threadIdx.y;
#pragma unroll
  for (int i = ty; i < 32; i += 8)
    t[i][tx] = toF(in[(long long)(r0 + i) * C + c0 + tx]);
  __syncthreads();
#pragma unroll
  for (int i = ty; i < 32; i += 8)
    out[(long long)(c0 + i) * R + r0 + tx] = __float2bfloat16(t[tx][i]);
}

// 3 input transposes (f32 [c][l] -> bf16 [l][c]) in one launch; z = 0..23
__global__ void transpose_in3(const float* __restrict__ q, const float* __restrict__ k,
                              const float* __restrict__ v, bf16* __restrict__ qT,
                              bf16* __restrict__ kT, bf16* __restrict__ vT) {
  __shared__ float t[32][33];
  const int z = blockIdx.z, bz = z & 7, which = z >> 3;
  const float* in = (which == 0 ? q : which == 1 ? k : v) + (size_t)bz * 1048576;
  bf16* out = (which == 0 ? qT : which == 1 ? kT : vT) + (size_t)bz * 1048576;
  const int r0 = blockIdx.y * 32, c0 = blockIdx.x * 32;
  const int tx = threadIdx.x, ty = threadIdx.y;
#pragma unroll
  for (int i = ty; i < 32; i += 8)
    t[i][tx] = in[(size_t)(r0 + i) * 1024 + c0 + tx];
  __syncthreads();
#pragma unroll
  for (int i = ty; i < 32; i += 8)
    out[(size_t)(c0 + i) * 1024 + r0 + tx] = __float2bfloat16(t[tx][i]);
}

// 4 weight casts in one launch; y selects the weight
__global__ void cast4(const float* __restrict__ w0, const float* __restrict__ w1,
                      const float* __restrict__ w2, const float* __restrict__ w3,
                      bf16* __restrict__ o0, bf16* __restrict__ o1,
                      bf16* __restrict__ o2, bf16* __restrict__ o3) {
  const int y = blockIdx.y;
  const float* in = y == 0 ? w0 : y == 1 ? w1 : y == 2 ? w2 : w3;
  bf16* out = y == 0 ? o0 : y == 1 ? o1 : y == 2 ? o2 : o3;
  int i = (blockIdx.x * 256 + threadIdx.x) * 4;
  float4 f = *(const float4*)(in + i);
  out[i + 0] = __float2bfloat16(f.x);
  out[i + 1] = __float2bfloat16(f.y);
  out[i + 2] = __float2bfloat16(f.z);
  out[i + 3] = __float2bfloat16(f.w);
}

extern "C" void kernel_launch(void* const* d_in, const int* in_sizes, int n_in,
                              void* d_out, int out_size, void* d_ws, size_t ws_size,
                              hipStream_t stream) {
  (void)in_sizes; (void)n_in; (void)out_size;
  const float* q  = (const float*)d_in[0];
  const float* k  = (const float*)d_in[1];
  const float* v  = (const float*)d_in[2];
  const float* Wq = (const float*)d_in[3];
  const float* bq = (const float*)d_in[4];
  const float* Wk = (const float*)d_in[5];
  const float* bk = (const float*)d_in[6];
  const float* Wv = (const float*)d_in[7];
  const float* bv = (const float*)d_in[8];
  const float* Wo = (const float*)d_in[9];
  const float* bo = (const float*)d_in[10];
  float* out = (float*)d_out;

  const size_t MB = 1ull << 20;
  if (ws_size < 152 * MB) return;
  char* ws = (char*)d_ws;
  bf16* qp    = (bf16*)(ws + 0 * MB);   // [B] flat head-blocked, Q*(log2e/8)
  bf16* kph   = (bf16*)(ws + 16 * MB);  // [B][16 h][1024 mm'][64 d]
  bf16* vptc  = (bf16*)(ws + 32 * MB);  // [B][16 h][32 chunk][64 d][32 mm']
  bf16* aout  = (bf16*)(ws + 48 * MB);  // [B] flat concat (h,m,d) == [ml][l]
  bf16* aoutT = (bf16*)(ws + 64 * MB);  // [B][l][ml]
  bf16* WoB   = (bf16*)(ws + 80 * MB);
  char* scr = ws + 82 * MB;
  bf16* WqB = (bf16*)(scr + 0 * MB);
  bf16* WkB = (bf16*)(scr + 2 * MB);
  bf16* WvB = (bf16*)(scr + 4 * MB);
  bf16* qT  = (bf16*)(scr + 6 * MB);
  bf16* kT  = (bf16*)(scr + 22 * MB);
  bf16* vT  = (bf16*)(scr + 38 * MB);

  const long long M1 = 1048576;
  dim3 tb(32, 8);

  cast4<<<dim3(1024, 4), 256, 0, stream>>>(Wq, Wk, Wv, Wo, WqB, WkB, WvB, WoB);
  transpose_in3<<<dim3(32, 32, 24), tb, 0, stream>>>(q, k, v, qT, kT, vT);
  // merged Q/K/V projections (3 x 256 blocks, 256x128 tiles)
  proj3<<<768, 256, 0, stream>>>(WqB, qT, qp, bq, kT, WkB, kph, bk, WvB, vT, vptc, bv);

  fused_attn<<<dim3(256), 1024, 0, stream>>>(qp, kph, vptc, aout);

  transpose_tile<bf16><<<dim3(32, 32, 8), tb, 0, stream>>>(aout, aoutT, 1024, 1024, M1, M1);
  gemm_out<<<512, 256, 0, stream>>>(WoB, aoutT, out, bo);
}

// Round 22
// 286.328 us; speedup vs baseline: 1.1148x; 1.1148x over previous
//
#include <hip/hip_runtime.h>
#include <hip/hip_bf16.h>
#include <cstdint>

using bf16 = __hip_bfloat16;
typedef __bf16 bf16x8 __attribute__((ext_vector_type(8)));
typedef float f32x4 __attribute__((ext_vector_type(4)));

#define DEV static __device__ __forceinline__

DEV float toF(float x) { return x; }
DEV float toF(bf16 x) { return __bfloat162float(x); }

DEV float lo2f(unsigned int u) { return __builtin_bit_cast(float, u << 16); }
DEV float hi2f(unsigned int u) { return __builtin_bit_cast(float, u & 0xffff0000u); }
// round-half-up bf16 pair pack (5 ops; bias ~2^-9 rel — negligible here)
DEV unsigned int pkr(float lo, float hi) {
  return ((__builtin_bit_cast(unsigned int, lo) + 0x8000u) >> 16) |
         ((__builtin_bit_cast(unsigned int, hi) + 0x8000u) & 0xffff0000u);
}
DEV float fexp2(float x) {  // D = 2^x
  float r;
  asm("v_exp_f32 %0, %1" : "=v"(r) : "v"(x));
  return r;
}
DEV float frcp(float x) {
  float r;
  asm("v_rcp_f32 %0, %1" : "=v"(r) : "v"(x));
  return r;
}

// async global->LDS, 16B per lane. LDS dest = wave-uniform base + lane*16.
DEV void gload_lds16(const void* g, void* l) {
  __builtin_amdgcn_global_load_lds(
      (const __attribute__((address_space(1))) unsigned int*)g,
      (__attribute__((address_space(3))) unsigned int*)l, 16, 0, 0);
}

// ---- GEMM core v3: 128x128 tile, BK=64, 4 waves (2x2, 64x64/wave).
// 16-B-chunk XOR swizzle (chunk ^= row&7) on the GLOBAL SOURCE (LDS dest
// linear per gload_lds rules) and on fragment reads -> ds_read_b128 2-way.
// Single-buffered: R18 (dbuf drain-0), R19 (counted vmcnt), R21 (256x128
// tile) all measured SLOWER — this is the measured optimum configuration.
#define GEMM_CORE128(A_, lda_, B_, ldb_)                                       \
  f32x4 acc[4][4] = {};                                                        \
  {                                                                            \
    const int wave = tid >> 6, lane = tid & 63;                                \
    const int wm = (wave >> 1) * 64, wn = (wave & 1) * 64;                     \
    const int lrow = lane & 15;                                                \
    const int g = lane >> 4;                                                   \
    const int xk = lrow & 7;                                                   \
    for (int k0 = 0; k0 < 1024; k0 += 64) {                                    \
      _Pragma("unroll") for (int r = 0; r < 4; ++r) {                          \
        int c = r * 256 + tid;                                                 \
        int row = c >> 3, sub = c & 7;                                         \
        gload_lds16(A_ + (long long)(m0 + row) * lda_ + k0 +                   \
                        ((sub ^ (row & 7)) << 3),                              \
                    (void*)(ldsA + (r * 256 + wave * 64) * 8));                \
      }                                                                        \
      _Pragma("unroll") for (int r = 0; r < 4; ++r) {                          \
        int c = r * 256 + tid;                                                 \
        int row = c >> 3, sub = c & 7;                                         \
        gload_lds16(B_ + (long long)(n0 + row) * ldb_ + k0 +                   \
                        ((sub ^ (row & 7)) << 3),                              \
                    (void*)(ldsB + (r * 256 + wave * 64) * 8));                \
      }                                                                        \
      __syncthreads();                                                         \
      _Pragma("unroll") for (int kc = 0; kc < 2; ++kc) {                       \
        bf16x8 af[4], bfr[4];                                                  \
        _Pragma("unroll") for (int i = 0; i < 4; ++i)                          \
            af[i] = *(const bf16x8*)&ldsA[(wm + i * 16 + lrow) * 64 +          \
                                          (((kc * 4 + g) ^ xk) << 3)];         \
        _Pragma("unroll") for (int j = 0; j < 4; ++j)                          \
            bfr[j] = *(const bf16x8*)&ldsB[(wn + j * 16 + lrow) * 64 +         \
                                           (((kc * 4 + g) ^ xk) << 3)];        \
        _Pragma("unroll") for (int i = 0; i < 4; ++i)                          \
            _Pragma("unroll") for (int j = 0; j < 4; ++j)                      \
                acc[i][j] = __builtin_amdgcn_mfma_f32_16x16x32_bf16(           \
                    af[i], bfr[j], acc[i][j], 0, 0, 0);                        \
      }                                                                        \
      __syncthreads();                                                         \
    }                                                                          \
  }

// Merged Q/K/V projection GEMMs: 1536 blocks; which = bid>>9 selects operands.
// which 0: qp = (Wq.q + bq)*log2e/8; 1: kph head-split = (kT.Wk^T + bk);
// 2: vptc chunk-split = (Wv.v + bv).
__launch_bounds__(256, 4)
__global__ void proj3(const bf16* __restrict__ Wq, const bf16* __restrict__ qT,
                      bf16* __restrict__ qp, const float* __restrict__ bq,
                      const bf16* __restrict__ kT, const bf16* __restrict__ Wk,
                      bf16* __restrict__ kph, const float* __restrict__ bk,
                      const bf16* __restrict__ Wv, const bf16* __restrict__ vT,
                      bf16* __restrict__ vptc, const float* __restrict__ bv) {
  __shared__ bf16 ldsA[128 * 64];
  __shared__ bf16 ldsB[128 * 64];
  const int tid = threadIdx.x;
  const int bid = blockIdx.x;
  const int which = bid >> 9, r0b = bid & 511;
  const long long z = r0b & 7;
  const int t = r0b >> 3;
  const int m0 = (t >> 3) * 128, n0 = (t & 7) * 128;
  const long long M1 = 1048576;

  const bf16* A;
  const bf16* B;
  const float* bias;
  bf16* C;
  float alpha;
  if (which == 0) {
    A = Wq; B = qT + z * M1; bias = bq; C = qp + z * M1; alpha = 0.18033688f;
  } else if (which == 1) {
    A = kT + z * M1; B = Wk; bias = bk; C = kph + z * M1; alpha = 1.0f;
  } else {
    A = Wv; B = vT + z * M1; bias = bv; C = vptc + z * M1; alpha = 1.0f;
  }

  GEMM_CORE128(A, 1024, B, 1024)

  const int wave = tid >> 6, lane = tid & 63;
  const int wm = (wave >> 1) * 64, wn = (wave & 1) * 64;
  const int lrow = lane & 15;
  const int r4 = (lane >> 4) * 4;
#pragma unroll
  for (int i = 0; i < 4; ++i) {
#pragma unroll
    for (int j = 0; j < 4; ++j) {
#pragma unroll
      for (int r = 0; r < 4; ++r) {
        int grow = m0 + wm + i * 16 + r4 + r;
        int gcol = n0 + wn + j * 16 + lrow;
        float vv = acc[i][j][r];
        if (which == 0) {
          vv = (vv + bias[grow]) * alpha;
          C[(long long)grow * 1024 + gcol] = __float2bfloat16(vv);
        } else if (which == 1) {
          vv += bias[gcol];
          long long idx = ((long long)(gcol >> 6) << 16) + grow * 64 + (gcol & 63);
          C[idx] = __float2bfloat16(vv);
        } else {
          vv += bias[grow];
          int mm = ((grow & 63) << 4) | (gcol >> 6);
          long long idx = ((long long)(grow >> 6) << 16) + ((mm >> 5) << 11) +
                          ((gcol & 63) << 5) + (mm & 31);
          C[idx] = __float2bfloat16(vv);
        }
      }
    }
  }
}

// Final projection: out = Wo . aoutT^T + bo, f32 out. 512 blocks, 128x128.
__launch_bounds__(256, 4)
__global__ void gemm_out(const bf16* __restrict__ Wo, const bf16* __restrict__ aoutT,
                         float* __restrict__ out, const float* __restrict__ bo) {
  __shared__ bf16 ldsA[128 * 64];
  __shared__ bf16 ldsB[128 * 64];
  const int tid = threadIdx.x;
  const int bid = blockIdx.x;
  const long long z = bid & 7;
  const int t = bid >> 3;
  const int m0 = (t >> 3) * 128, n0 = (t & 7) * 128;
  const long long M1 = 1048576;
  const bf16* A = Wo;
  const bf16* B = aoutT + z * M1;
  float* C = out + z * M1;

  GEMM_CORE128(A, 1024, B, 1024)

  const int wave = tid >> 6, lane = tid & 63;
  const int wm = (wave >> 1) * 64, wn = (wave & 1) * 64;
  const int lrow = lane & 15;
  const int r4 = (lane >> 4) * 4;
#pragma unroll
  for (int i = 0; i < 4; ++i)
#pragma unroll
    for (int j = 0; j < 4; ++j)
#pragma unroll
      for (int r = 0; r < 4; ++r) {
        int grow = m0 + wm + i * 16 + r4 + r;
        int gcol = n0 + wn + j * 16 + lrow;
        C[(long long)grow * 1024 + gcol] = acc[i][j][r] + bo[grow];
      }
}

// QK^T for one 64-wide mm' chunk of the wave's own head, S -> SPn (bf16 pairs)
#define QK_CHUNK(itv, SPn)                                                     \
  {                                                                            \
    const int mm0 = (itv) * 64;                                                \
    _Pragma("unroll") for (int mmf = 0; mmf < 4; ++mmf) {                      \
      const bf16* kr = Kb + (size_t)(mm0 + mmf * 16 + l15) * 64 + g * 8;       \
      bf16x8 k0 = *(const bf16x8*)kr;                                          \
      bf16x8 k1 = *(const bf16x8*)(kr + 32);                                   \
      f32x4 sa = {}, sb = {};                                                  \
      __builtin_amdgcn_s_setprio(1);                                           \
      sa = __builtin_amdgcn_mfma_f32_16x16x32_bf16(k0, qf[0][0], sa, 0, 0, 0); \
      sa = __builtin_amdgcn_mfma_f32_16x16x32_bf16(k1, qf[0][1], sa, 0, 0, 0); \
      sb = __builtin_amdgcn_mfma_f32_16x16x32_bf16(k0, qf[1][0], sb, 0, 0, 0); \
      sb = __builtin_amdgcn_mfma_f32_16x16x32_bf16(k1, qf[1][1], sb, 0, 0, 0); \
      __builtin_amdgcn_s_setprio(0);                                           \
      uint2 ua, ub;                                                            \
      ua.x = pkr(sa[0], sa[1]);                                                \
      ua.y = pkr(sa[2], sa[3]);                                                \
      ub.x = pkr(sb[0], sb[1]);                                                \
      ub.y = pkr(sb[2], sb[3]);                                                \
      *(uint2*)&(SPn)[hrow + l15 * 35 + mmf * 8 + g * 2] = ua;                 \
      *(uint2*)&(SPn)[hrow + (16 + l15) * 35 + mmf * 8 + g * 2] = ub;          \
    }                                                                          \
  }

// Fused attn, PIPELINED: 16 waves (=heads), 32-row m-tile, mm-chunk 64,
// double-buffered SP (2 x [16][32][35] u32 = 140KB). Per iter:
// {QK(it+1)->SPnext || softmax(it) on SPcur} -> barrier -> PV(it) (no trailing
// barrier: QK/PV touch only own-head rows; softmax works the other buffer).
// qp holds Q*(log2e/8) -> softmax = raw v_exp_f32, NO max-subtraction
// (scores bounded: std 0.41, |S|max ~2.4 -> exp<=11, f32-safe).
__launch_bounds__(1024, 4)
__global__ void fused_attn(const bf16* __restrict__ qp,
                           const bf16* __restrict__ kph,
                           const bf16* __restrict__ vptc,
                           bf16* __restrict__ aout) {
  __shared__ unsigned int SP[2][16 * 32 * 35];  // 2 x 70KB
  const int bid = blockIdx.x;
  const int bb = bid & 7, mt = bid >> 3;  // batch -> XCD
  const int tid = threadIdx.x;
  const int w = tid >> 6, lane = tid & 63;  // wave = head
  const int l15 = lane & 15, g = lane >> 4;

  const bf16* Qb = qp + ((size_t)bb << 20);
  const bf16* Kb = kph + ((size_t)bb << 20) + ((size_t)w << 16);
  const bf16* Vb = vptc + ((size_t)bb << 20) + ((size_t)w << 16);
  bf16* Ob = aout + ((size_t)bb << 20);

  // hoist this wave's head's Q fragments: 2 m-frags x 2 k-chunks (16 VGPRs)
  bf16x8 qf[2][2];
#pragma unroll
  for (int mf = 0; mf < 2; ++mf)
#pragma unroll
    for (int kc = 0; kc < 2; ++kc)
      qf[mf][kc] = *(const bf16x8*)(Qb + ((size_t)w << 16) +
                                    (mt * 32 + mf * 16 + l15) * 64 + kc * 32 + g * 8);

  f32x4 oacc[2][4] = {};
  const unsigned int hrow = w * 1120;  // own head's LDS base (u32), 32*35
  const int smbase = (tid >> 5) * 35 + (tid & 31);  // 1 softmax slot/thread

  QK_CHUNK(0, SP[0])
  __syncthreads();

  for (int it = 0; it < 16; ++it) {
    unsigned int* SPc = SP[it & 1];
    // ---- QK(it+1) into the other buffer (own head rows only) ----
    if (it < 15) QK_CHUNK(it + 1, SP[(it + 1) & 1])
    // ---- softmax(it) over 16 heads on SPc: single pass, exp2 domain ----
    {
      float el[16], eh[16];
#pragma unroll
      for (int h = 0; h < 16; ++h) {
        unsigned int u = SPc[h * 1120 + smbase];
        el[h] = fexp2(lo2f(u));
        eh[h] = fexp2(hi2f(u));
      }
      float sl = (((el[0] + el[1]) + (el[2] + el[3])) + ((el[4] + el[5]) + (el[6] + el[7]))) +
                 (((el[8] + el[9]) + (el[10] + el[11])) + ((el[12] + el[13]) + (el[14] + el[15])));
      float sh = (((eh[0] + eh[1]) + (eh[2] + eh[3])) + ((eh[4] + eh[5]) + (eh[6] + eh[7]))) +
                 (((eh[8] + eh[9]) + (eh[10] + eh[11])) + ((eh[12] + eh[13]) + (eh[14] + eh[15])));
      float il = frcp(sl), ih = frcp(sh);
#pragma unroll
      for (int h = 0; h < 16; ++h)
        SPc[h * 1120 + smbase] = pkr(el[h] * il, eh[h] * ih);
    }
    __syncthreads();
    // ---- PV(it) for own head over the 64 mm' just normalized ----
#pragma unroll
    for (int c = 0; c < 2; ++c) {
      uint4 pa0 = *(const uint4*)&SPc[hrow + l15 * 35 + c * 16 + g * 4];
      uint4 pa1 = *(const uint4*)&SPc[hrow + (16 + l15) * 35 + c * 16 + g * 4];
      bf16x8 p0 = __builtin_bit_cast(bf16x8, pa0);
      bf16x8 p1 = __builtin_bit_cast(bf16x8, pa1);
      const bf16* vb = Vb + ((it * 2 + c) << 11) + g * 8;
      __builtin_amdgcn_s_setprio(1);
#pragma unroll
      for (int dj = 0; dj < 4; ++dj) {
        bf16x8 vf = *(const bf16x8*)(vb + (dj * 16 + l15) * 32);
        oacc[0][dj] = __builtin_amdgcn_mfma_f32_16x16x32_bf16(p0, vf, oacc[0][dj], 0, 0, 0);
        oacc[1][dj] = __builtin_amdgcn_mfma_f32_16x16x32_bf16(p1, vf, oacc[1][dj], 0, 0, 0);
      }
      __builtin_amdgcn_s_setprio(0);
    }
    // no trailing barrier: QK(it+2) writes own-head rows of SPc; other waves'
    // PV(it) reads are also own-head rows (disjoint); softmax(it+1) reads the
    // OTHER buffer, whose writes were sealed by the post-softmax barrier.
  }
  // ---- write out flat (h, m, dt) concat layout ----
#pragma unroll
  for (int mf = 0; mf < 2; ++mf)
#pragma unroll
    for (int dj = 0; dj < 4; ++dj)
#pragma unroll
      for (int r = 0; r < 4; ++r)
        Ob[((size_t)w << 16) + (size_t)(mt * 32 + mf * 16 + g * 4 + r) * 64 +
           dj * 16 + l15] = __float2bfloat16(oacc[mf][dj][r]);
}

// out[c][r] = (bf16) in[r][c]
template <typename TIN>
__global__ void transpose_tile(const TIN* __restrict__ in, bf16* __restrict__ out,
                               int R, int C, long long sIn, long long sOut) {
  __shared__ float t[32][33];
  const long long z = blockIdx.z;
  in += z * sIn;
  out += z * sOut;
  const int r0 = blockIdx.y * 32, c0 = blockIdx.x * 32;
  const int tx = threadIdx.x, ty = threadIdx.y;
#pragma unroll
  for (int i = ty; i < 32; i += 8)
    t[i][tx] = toF(in[(long long)(r0 + i) * C + c0 + tx]);
  __syncthreads();
#pragma unroll
  for (int i = ty; i < 32; i += 8)
    out[(long long)(c0 + i) * R + r0 + tx] = __float2bfloat16(t[tx][i]);
}

// 3 input transposes (f32 [c][l] -> bf16 [l][c]) in one launch; z = 0..23
__global__ void transpose_in3(const float* __restrict__ q, const float* __restrict__ k,
                              const float* __restrict__ v, bf16* __restrict__ qT,
                              bf16* __restrict__ kT, bf16* __restrict__ vT) {
  __shared__ float t[32][33];
  const int z = blockIdx.z, bz = z & 7, which = z >> 3;
  const float* in = (which == 0 ? q : which == 1 ? k : v) + (size_t)bz * 1048576;
  bf16* out = (which == 0 ? qT : which == 1 ? kT : vT) + (size_t)bz * 1048576;
  const int r0 = blockIdx.y * 32, c0 = blockIdx.x * 32;
  const int tx = threadIdx.x, ty = threadIdx.y;
#pragma unroll
  for (int i = ty; i < 32; i += 8)
    t[i][tx] = in[(size_t)(r0 + i) * 1024 + c0 + tx];
  __syncthreads();
#pragma unroll
  for (int i = ty; i < 32; i += 8)
    out[(size_t)(c0 + i) * 1024 + r0 + tx] = __float2bfloat16(t[tx][i]);
}

// 4 weight casts in one launch; y selects the weight
__global__ void cast4(const float* __restrict__ w0, const float* __restrict__ w1,
                      const float* __restrict__ w2, const float* __restrict__ w3,
                      bf16* __restrict__ o0, bf16* __restrict__ o1,
                      bf16* __restrict__ o2, bf16* __restrict__ o3) {
  const int y = blockIdx.y;
  const float* in = y == 0 ? w0 : y == 1 ? w1 : y == 2 ? w2 : w3;
  bf16* out = y == 0 ? o0 : y == 1 ? o1 : y == 2 ? o2 : o3;
  int i = (blockIdx.x * 256 + threadIdx.x) * 4;
  float4 f = *(const float4*)(in + i);
  out[i + 0] = __float2bfloat16(f.x);
  out[i + 1] = __float2bfloat16(f.y);
  out[i + 2] = __float2bfloat16(f.z);
  out[i + 3] = __float2bfloat16(f.w);
}

extern "C" void kernel_launch(void* const* d_in, const int* in_sizes, int n_in,
                              void* d_out, int out_size, void* d_ws, size_t ws_size,
                              hipStream_t stream) {
  (void)in_sizes; (void)n_in; (void)out_size;
  const float* q  = (const float*)d_in[0];
  const float* k  = (const float*)d_in[1];
  const float* v  = (const float*)d_in[2];
  const float* Wq = (const float*)d_in[3];
  const float* bq = (const float*)d_in[4];
  const float* Wk = (const float*)d_in[5];
  const float* bk = (const float*)d_in[6];
  const float* Wv = (const float*)d_in[7];
  const float* bv = (const float*)d_in[8];
  const float* Wo = (const float*)d_in[9];
  const float* bo = (const float*)d_in[10];
  float* out = (float*)d_out;

  const size_t MB = 1ull << 20;
  if (ws_size < 152 * MB) return;
  char* ws = (char*)d_ws;
  bf16* qp    = (bf16*)(ws + 0 * MB);   // [B] flat head-blocked, Q*(log2e/8)
  bf16* kph   = (bf16*)(ws + 16 * MB);  // [B][16 h][1024 mm'][64 d]
  bf16* vptc  = (bf16*)(ws + 32 * MB);  // [B][16 h][32 chunk][64 d][32 mm']
  bf16* aout  = (bf16*)(ws + 48 * MB);  // [B] flat concat (h,m,d) == [ml][l]
  bf16* aoutT = (bf16*)(ws + 64 * MB);  // [B][l][ml]
  bf16* WoB   = (bf16*)(ws + 80 * MB);
  char* scr = ws + 82 * MB;
  bf16* WqB = (bf16*)(scr + 0 * MB);
  bf16* WkB = (bf16*)(scr + 2 * MB);
  bf16* WvB = (bf16*)(scr + 4 * MB);
  bf16* qT  = (bf16*)(scr + 6 * MB);
  bf16* kT  = (bf16*)(scr + 22 * MB);
  bf16* vT  = (bf16*)(scr + 38 * MB);

  const long long M1 = 1048576;
  dim3 tb(32, 8);

  cast4<<<dim3(1024, 4), 256, 0, stream>>>(Wq, Wk, Wv, Wo, WqB, WkB, WvB, WoB);
  transpose_in3<<<dim3(32, 32, 24), tb, 0, stream>>>(q, k, v, qT, kT, vT);
  // merged Q/K/V projections (3 x 512 blocks, 128x128 tiles)
  proj3<<<1536, 256, 0, stream>>>(WqB, qT, qp, bq, kT, WkB, kph, bk, WvB, vT, vptc, bv);

  fused_attn<<<dim3(256), 1024, 0, stream>>>(qp, kph, vptc, aout);

  transpose_tile<bf16><<<dim3(32, 32, 8), tb, 0, stream>>>(aout, aoutT, 1024, 1024, M1, M1);
  gemm_out<<<512, 256, 0, stream>>>(WoB, aoutT, out, bo);
}

// Round 23
// 282.631 us; speedup vs baseline: 1.1294x; 1.0131x over previous
//
#include <hip/hip_runtime.h>
#include <hip/hip_bf16.h>
#include <cstdint>

using bf16 = __hip_bfloat16;
typedef __bf16 bf16x8 __attribute__((ext_vector_type(8)));
typedef float f32x4 __attribute__((ext_vector_type(4)));

#define DEV static __device__ __forceinline__

DEV float toF(float x) { return x; }
DEV float toF(bf16 x) { return __bfloat162float(x); }

DEV float lo2f(unsigned int u) { return __builtin_bit_cast(float, u << 16); }
DEV float hi2f(unsigned int u) { return __builtin_bit_cast(float, u & 0xffff0000u); }
// round-half-up bf16 pair pack (5 ops; bias ~2^-9 rel — negligible here)
DEV unsigned int pkr(float lo, float hi) {
  return ((__builtin_bit_cast(unsigned int, lo) + 0x8000u) >> 16) |
         ((__builtin_bit_cast(unsigned int, hi) + 0x8000u) & 0xffff0000u);
}
DEV float fexp2(float x) {  // D = 2^x
  float r;
  asm("v_exp_f32 %0, %1" : "=v"(r) : "v"(x));
  return r;
}
DEV float frcp(float x) {
  float r;
  asm("v_rcp_f32 %0, %1" : "=v"(r) : "v"(x));
  return r;
}

// async global->LDS, 16B per lane. LDS dest = wave-uniform base + lane*16.
DEV void gload_lds16(const void* g, void* l) {
  __builtin_amdgcn_global_load_lds(
      (const __attribute__((address_space(1))) unsigned int*)g,
      (__attribute__((address_space(3))) unsigned int*)l, 16, 0, 0);
}

// ---- GEMM core v3: 128x128 tile, BK=64, 4 waves (2x2, 64x64/wave).
// 16-B-chunk XOR swizzle (chunk ^= row&7) on the GLOBAL SOURCE (LDS dest
// linear per gload_lds rules) and on fragment reads -> ds_read_b128 2-way.
// Single-buffered: R18 (dbuf drain-0), R19 (counted vmcnt), R21 (256x128
// tile) all measured SLOWER — this is the measured optimum configuration.
#define GEMM_CORE128(A_, lda_, B_, ldb_)                                       \
  f32x4 acc[4][4] = {};                                                        \
  {                                                                            \
    const int wave = tid >> 6, lane = tid & 63;                                \
    const int wm = (wave >> 1) * 64, wn = (wave & 1) * 64;                     \
    const int lrow = lane & 15;                                                \
    const int g = lane >> 4;                                                   \
    const int xk = lrow & 7;                                                   \
    for (int k0 = 0; k0 < 1024; k0 += 64) {                                    \
      _Pragma("unroll") for (int r = 0; r < 4; ++r) {                          \
        int c = r * 256 + tid;                                                 \
        int row = c >> 3, sub = c & 7;                                         \
        gload_lds16(A_ + (long long)(m0 + row) * lda_ + k0 +                   \
                        ((sub ^ (row & 7)) << 3),                              \
                    (void*)(ldsA + (r * 256 + wave * 64) * 8));                \
      }                                                                        \
      _Pragma("unroll") for (int r = 0; r < 4; ++r) {                          \
        int c = r * 256 + tid;                                                 \
        int row = c >> 3, sub = c & 7;                                         \
        gload_lds16(B_ + (long long)(n0 + row) * ldb_ + k0 +                   \
                        ((sub ^ (row & 7)) << 3),                              \
                    (void*)(ldsB + (r * 256 + wave * 64) * 8));                \
      }                                                                        \
      __syncthreads();                                                         \
      _Pragma("unroll") for (int kc = 0; kc < 2; ++kc) {                       \
        bf16x8 af[4], bfr[4];                                                  \
        _Pragma("unroll") for (int i = 0; i < 4; ++i)                          \
            af[i] = *(const bf16x8*)&ldsA[(wm + i * 16 + lrow) * 64 +          \
                                          (((kc * 4 + g) ^ xk) << 3)];         \
        _Pragma("unroll") for (int j = 0; j < 4; ++j)                          \
            bfr[j] = *(const bf16x8*)&ldsB[(wn + j * 16 + lrow) * 64 +         \
                                           (((kc * 4 + g) ^ xk) << 3)];        \
        _Pragma("unroll") for (int i = 0; i < 4; ++i)                          \
            _Pragma("unroll") for (int j = 0; j < 4; ++j)                      \
                acc[i][j] = __builtin_amdgcn_mfma_f32_16x16x32_bf16(           \
                    af[i], bfr[j], acc[i][j], 0, 0, 0);                        \
      }                                                                        \
      __syncthreads();                                                         \
    }                                                                          \
  }

// Merged Q/K/V projection GEMMs: 1536 blocks; which = bid>>9 selects operands.
// which 0: qp = (Wq.q + bq)*log2e/8; 1: kph head-split = (kT.Wk^T + bk);
// 2: vptc chunk-split = (Wv.v + bv).
__launch_bounds__(256, 4)
__global__ void proj3(const bf16* __restrict__ Wq, const bf16* __restrict__ qT,
                      bf16* __restrict__ qp, const float* __restrict__ bq,
                      const bf16* __restrict__ kT, const bf16* __restrict__ Wk,
                      bf16* __restrict__ kph, const float* __restrict__ bk,
                      const bf16* __restrict__ Wv, const bf16* __restrict__ vT,
                      bf16* __restrict__ vptc, const float* __restrict__ bv) {
  __shared__ bf16 ldsA[128 * 64];
  __shared__ bf16 ldsB[128 * 64];
  const int tid = threadIdx.x;
  const int bid = blockIdx.x;
  const int which = bid >> 9, r0b = bid & 511;
  const long long z = r0b & 7;
  const int t = r0b >> 3;
  const int m0 = (t >> 3) * 128, n0 = (t & 7) * 128;
  const long long M1 = 1048576;

  const bf16* A;
  const bf16* B;
  const float* bias;
  bf16* C;
  float alpha;
  if (which == 0) {
    A = Wq; B = qT + z * M1; bias = bq; C = qp + z * M1; alpha = 0.18033688f;
  } else if (which == 1) {
    A = kT + z * M1; B = Wk; bias = bk; C = kph + z * M1; alpha = 1.0f;
  } else {
    A = Wv; B = vT + z * M1; bias = bv; C = vptc + z * M1; alpha = 1.0f;
  }

  GEMM_CORE128(A, 1024, B, 1024)

  const int wave = tid >> 6, lane = tid & 63;
  const int wm = (wave >> 1) * 64, wn = (wave & 1) * 64;
  const int lrow = lane & 15;
  const int r4 = (lane >> 4) * 4;
#pragma unroll
  for (int i = 0; i < 4; ++i) {
#pragma unroll
    for (int j = 0; j < 4; ++j) {
#pragma unroll
      for (int r = 0; r < 4; ++r) {
        int grow = m0 + wm + i * 16 + r4 + r;
        int gcol = n0 + wn + j * 16 + lrow;
        float vv = acc[i][j][r];
        if (which == 0) {
          vv = (vv + bias[grow]) * alpha;
          C[(long long)grow * 1024 + gcol] = __float2bfloat16(vv);
        } else if (which == 1) {
          vv += bias[gcol];
          long long idx = ((long long)(gcol >> 6) << 16) + grow * 64 + (gcol & 63);
          C[idx] = __float2bfloat16(vv);
        } else {
          vv += bias[grow];
          int mm = ((grow & 63) << 4) | (gcol >> 6);
          long long idx = ((long long)(grow >> 6) << 16) + ((mm >> 5) << 11) +
                          ((gcol & 63) << 5) + (mm & 31);
          C[idx] = __float2bfloat16(vv);
        }
      }
    }
  }
}

// Final projection: out = Wo . aoutT^T + bo, f32 out. 512 blocks, 128x128.
__launch_bounds__(256, 4)
__global__ void gemm_out(const bf16* __restrict__ Wo, const bf16* __restrict__ aoutT,
                         float* __restrict__ out, const float* __restrict__ bo) {
  __shared__ bf16 ldsA[128 * 64];
  __shared__ bf16 ldsB[128 * 64];
  const int tid = threadIdx.x;
  const int bid = blockIdx.x;
  const long long z = bid & 7;
  const int t = bid >> 3;
  const int m0 = (t >> 3) * 128, n0 = (t & 7) * 128;
  const long long M1 = 1048576;
  const bf16* A = Wo;
  const bf16* B = aoutT + z * M1;
  float* C = out + z * M1;

  GEMM_CORE128(A, 1024, B, 1024)

  const int wave = tid >> 6, lane = tid & 63;
  const int wm = (wave >> 1) * 64, wn = (wave & 1) * 64;
  const int lrow = lane & 15;
  const int r4 = (lane >> 4) * 4;
#pragma unroll
  for (int i = 0; i < 4; ++i)
#pragma unroll
    for (int j = 0; j < 4; ++j)
#pragma unroll
      for (int r = 0; r < 4; ++r) {
        int grow = m0 + wm + i * 16 + r4 + r;
        int gcol = n0 + wn + j * 16 + lrow;
        C[(long long)grow * 1024 + gcol] = acc[i][j][r] + bo[grow];
      }
}

// QK^T for one 64-wide mm' chunk of the wave's own head, S -> SPn (bf16 pairs)
#define QK_CHUNK(itv, SPn)                                                     \
  {                                                                            \
    const int mm0 = (itv) * 64;                                                \
    _Pragma("unroll") for (int mmf = 0; mmf < 4; ++mmf) {                      \
      const bf16* kr = Kb + (size_t)(mm0 + mmf * 16 + l15) * 64 + g * 8;       \
      bf16x8 k0 = *(const bf16x8*)kr;                                          \
      bf16x8 k1 = *(const bf16x8*)(kr + 32);                                   \
      f32x4 sa = {}, sb = {};                                                  \
      __builtin_amdgcn_s_setprio(1);                                           \
      sa = __builtin_amdgcn_mfma_f32_16x16x32_bf16(k0, qf[0][0], sa, 0, 0, 0); \
      sa = __builtin_amdgcn_mfma_f32_16x16x32_bf16(k1, qf[0][1], sa, 0, 0, 0); \
      sb = __builtin_amdgcn_mfma_f32_16x16x32_bf16(k0, qf[1][0], sb, 0, 0, 0); \
      sb = __builtin_amdgcn_mfma_f32_16x16x32_bf16(k1, qf[1][1], sb, 0, 0, 0); \
      __builtin_amdgcn_s_setprio(0);                                           \
      uint2 ua, ub;                                                            \
      ua.x = pkr(sa[0], sa[1]);                                                \
      ua.y = pkr(sa[2], sa[3]);                                                \
      ub.x = pkr(sb[0], sb[1]);                                                \
      ub.y = pkr(sb[2], sb[3]);                                                \
      *(uint2*)&(SPn)[hrow + l15 * 35 + mmf * 8 + g * 2] = ua;                 \
      *(uint2*)&(SPn)[hrow + (16 + l15) * 35 + mmf * 8 + g * 2] = ub;          \
    }                                                                          \
  }

// Fused attn, PIPELINED: 16 waves (=heads), 32-row m-tile, mm-chunk 64,
// double-buffered SP (2 x [16][32][35] u32 = 140KB). Per iter:
// {QK(it+1)->SPnext || softmax(it) on SPcur} -> barrier -> PV(it) (no trailing
// barrier: QK/PV touch only own-head rows; softmax works the other buffer).
// qp holds Q*(log2e/8) -> softmax = raw v_exp_f32, NO max-subtraction
// (scores bounded: std 0.41, |S|max ~2.4 -> exp<=11, f32-safe).
__launch_bounds__(1024, 4)
__global__ void fused_attn(const bf16* __restrict__ qp,
                           const bf16* __restrict__ kph,
                           const bf16* __restrict__ vptc,
                           bf16* __restrict__ aout) {
  __shared__ unsigned int SP[2][16 * 32 * 35];  // 2 x 70KB
  const int bid = blockIdx.x;
  const int bb = bid & 7, mt = bid >> 3;  // batch -> XCD
  const int tid = threadIdx.x;
  const int w = tid >> 6, lane = tid & 63;  // wave = head
  const int l15 = lane & 15, g = lane >> 4;

  const bf16* Qb = qp + ((size_t)bb << 20);
  const bf16* Kb = kph + ((size_t)bb << 20) + ((size_t)w << 16);
  const bf16* Vb = vptc + ((size_t)bb << 20) + ((size_t)w << 16);
  bf16* Ob = aout + ((size_t)bb << 20);

  // hoist this wave's head's Q fragments: 2 m-frags x 2 k-chunks (16 VGPRs)
  bf16x8 qf[2][2];
#pragma unroll
  for (int mf = 0; mf < 2; ++mf)
#pragma unroll
    for (int kc = 0; kc < 2; ++kc)
      qf[mf][kc] = *(const bf16x8*)(Qb + ((size_t)w << 16) +
                                    (mt * 32 + mf * 16 + l15) * 64 + kc * 32 + g * 8);

  f32x4 oacc[2][4] = {};
  const unsigned int hrow = w * 1120;  // own head's LDS base (u32), 32*35
  const int smbase = (tid >> 5) * 35 + (tid & 31);  // 1 softmax slot/thread

  QK_CHUNK(0, SP[0])
  __syncthreads();

  for (int it = 0; it < 16; ++it) {
    unsigned int* SPc = SP[it & 1];
    // ---- QK(it+1) into the other buffer (own head rows only) ----
    if (it < 15) QK_CHUNK(it + 1, SP[(it + 1) & 1])
    // ---- softmax(it) over 16 heads on SPc: single pass, exp2 domain ----
    {
      float el[16], eh[16];
#pragma unroll
      for (int h = 0; h < 16; ++h) {
        unsigned int u = SPc[h * 1120 + smbase];
        el[h] = fexp2(lo2f(u));
        eh[h] = fexp2(hi2f(u));
      }
      float sl = (((el[0] + el[1]) + (el[2] + el[3])) + ((el[4] + el[5]) + (el[6] + el[7]))) +
                 (((el[8] + el[9]) + (el[10] + el[11])) + ((el[12] + el[13]) + (el[14] + el[15])));
      float sh = (((eh[0] + eh[1]) + (eh[2] + eh[3])) + ((eh[4] + eh[5]) + (eh[6] + eh[7]))) +
                 (((eh[8] + eh[9]) + (eh[10] + eh[11])) + ((eh[12] + eh[13]) + (eh[14] + eh[15])));
      float il = frcp(sl), ih = frcp(sh);
#pragma unroll
      for (int h = 0; h < 16; ++h)
        SPc[h * 1120 + smbase] = pkr(el[h] * il, eh[h] * ih);
    }
    __syncthreads();
    // ---- PV(it) for own head over the 64 mm' just normalized ----
#pragma unroll
    for (int c = 0; c < 2; ++c) {
      uint4 pa0 = *(const uint4*)&SPc[hrow + l15 * 35 + c * 16 + g * 4];
      uint4 pa1 = *(const uint4*)&SPc[hrow + (16 + l15) * 35 + c * 16 + g * 4];
      bf16x8 p0 = __builtin_bit_cast(bf16x8, pa0);
      bf16x8 p1 = __builtin_bit_cast(bf16x8, pa1);
      const bf16* vb = Vb + ((it * 2 + c) << 11) + g * 8;
      __builtin_amdgcn_s_setprio(1);
#pragma unroll
      for (int dj = 0; dj < 4; ++dj) {
        bf16x8 vf = *(const bf16x8*)(vb + (dj * 16 + l15) * 32);
        oacc[0][dj] = __builtin_amdgcn_mfma_f32_16x16x32_bf16(p0, vf, oacc[0][dj], 0, 0, 0);
        oacc[1][dj] = __builtin_amdgcn_mfma_f32_16x16x32_bf16(p1, vf, oacc[1][dj], 0, 0, 0);
      }
      __builtin_amdgcn_s_setprio(0);
    }
    // no trailing barrier: QK(it+2) writes own-head rows of SPc; other waves'
    // PV(it) reads are also own-head rows (disjoint); softmax(it+1) reads the
    // OTHER buffer, whose writes were sealed by the post-softmax barrier.
  }
  // ---- write out flat (h, m, dt) concat layout ----
#pragma unroll
  for (int mf = 0; mf < 2; ++mf)
#pragma unroll
    for (int dj = 0; dj < 4; ++dj)
#pragma unroll
      for (int r = 0; r < 4; ++r)
        Ob[((size_t)w << 16) + (size_t)(mt * 32 + mf * 16 + g * 4 + r) * 64 +
           dj * 16 + l15] = __float2bfloat16(oacc[mf][dj][r]);
}

// out[c][r] = (bf16) in[r][c]
template <typename TIN>
__global__ void transpose_tile(const TIN* __restrict__ in, bf16* __restrict__ out,
                               int R, int C, long long sIn, long long sOut) {
  __shared__ float t[32][33];
  const long long z = blockIdx.z;
  in += z * sIn;
  out += z * sOut;
  const int r0 = blockIdx.y * 32, c0 = blockIdx.x * 32;
  const int tx = threadIdx.x, ty = threadIdx.y;
#pragma unroll
  for (int i = ty; i < 32; i += 8)
    t[i][tx] = toF(in[(long long)(r0 + i) * C + c0 + tx]);
  __syncthreads();
#pragma unroll
  for (int i = ty; i < 32; i += 8)
    out[(long long)(c0 + i) * R + r0 + tx] = __float2bfloat16(t[tx][i]);
}

// Merged preprocessing, ONE dispatch: z = 0..23 input transposes
// (f32 [c][l] -> bf16 [l][c]); z = 24..27 weight casts (f32 -> bf16).
// Both paths value-identical to the previous cast4 + transpose_in3 pair.
__global__ void prep(const float* __restrict__ q, const float* __restrict__ k,
                     const float* __restrict__ v, bf16* __restrict__ qT,
                     bf16* __restrict__ kT, bf16* __restrict__ vT,
                     const float* __restrict__ w0, const float* __restrict__ w1,
                     const float* __restrict__ w2, const float* __restrict__ w3,
                     bf16* __restrict__ o0, bf16* __restrict__ o1,
                     bf16* __restrict__ o2, bf16* __restrict__ o3) {
  __shared__ float t[32][33];
  const int z = blockIdx.z;
  const int tx = threadIdx.x, ty = threadIdx.y;
  if (z >= 24) {
    const int y = z - 24;
    const float* in = y == 0 ? w0 : y == 1 ? w1 : y == 2 ? w2 : w3;
    bf16* out = y == 0 ? o0 : y == 1 ? o1 : y == 2 ? o2 : o3;
    int i = (((blockIdx.y * 32 + blockIdx.x) * 256) + ty * 32 + tx) * 4;
    float4 f = *(const float4*)(in + i);
    out[i + 0] = __float2bfloat16(f.x);
    out[i + 1] = __float2bfloat16(f.y);
    out[i + 2] = __float2bfloat16(f.z);
    out[i + 3] = __float2bfloat16(f.w);
    return;
  }
  const int bz = z & 7, which = z >> 3;
  const float* in = (which == 0 ? q : which == 1 ? k : v) + (size_t)bz * 1048576;
  bf16* out = (which == 0 ? qT : which == 1 ? kT : vT) + (size_t)bz * 1048576;
  const int r0 = blockIdx.y * 32, c0 = blockIdx.x * 32;
#pragma unroll
  for (int i = ty; i < 32; i += 8)
    t[i][tx] = in[(size_t)(r0 + i) * 1024 + c0 + tx];
  __syncthreads();
#pragma unroll
  for (int i = ty; i < 32; i += 8)
    out[(size_t)(c0 + i) * 1024 + r0 + tx] = __float2bfloat16(t[tx][i]);
}

extern "C" void kernel_launch(void* const* d_in, const int* in_sizes, int n_in,
                              void* d_out, int out_size, void* d_ws, size_t ws_size,
                              hipStream_t stream) {
  (void)in_sizes; (void)n_in; (void)out_size;
  const float* q  = (const float*)d_in[0];
  const float* k  = (const float*)d_in[1];
  const float* v  = (const float*)d_in[2];
  const float* Wq = (const float*)d_in[3];
  const float* bq = (const float*)d_in[4];
  const float* Wk = (const float*)d_in[5];
  const float* bk = (const float*)d_in[6];
  const float* Wv = (const float*)d_in[7];
  const float* bv = (const float*)d_in[8];
  const float* Wo = (const float*)d_in[9];
  const float* bo = (const float*)d_in[10];
  float* out = (float*)d_out;

  const size_t MB = 1ull << 20;
  if (ws_size < 152 * MB) return;
  char* ws = (char*)d_ws;
  bf16* qp    = (bf16*)(ws + 0 * MB);   // [B] flat head-blocked, Q*(log2e/8)
  bf16* kph   = (bf16*)(ws + 16 * MB);  // [B][16 h][1024 mm'][64 d]
  bf16* vptc  = (bf16*)(ws + 32 * MB);  // [B][16 h][32 chunk][64 d][32 mm']
  bf16* aout  = (bf16*)(ws + 48 * MB);  // [B] flat concat (h,m,d) == [ml][l]
  bf16* aoutT = (bf16*)(ws + 64 * MB);  // [B][l][ml]
  bf16* WoB   = (bf16*)(ws + 80 * MB);
  char* scr = ws + 82 * MB;
  bf16* WqB = (bf16*)(scr + 0 * MB);
  bf16* WkB = (bf16*)(scr + 2 * MB);
  bf16* WvB = (bf16*)(scr + 4 * MB);
  bf16* qT  = (bf16*)(scr + 6 * MB);
  bf16* kT  = (bf16*)(scr + 22 * MB);
  bf16* vT  = (bf16*)(scr + 38 * MB);

  const long long M1 = 1048576;
  dim3 tb(32, 8);

  // merged input transposes + weight casts (one dispatch)
  prep<<<dim3(32, 32, 28), tb, 0, stream>>>(q, k, v, qT, kT, vT,
                                            Wq, Wk, Wv, Wo, WqB, WkB, WvB, WoB);
  // merged Q/K/V projections (3 x 512 blocks, 128x128 tiles)
  proj3<<<1536, 256, 0, stream>>>(WqB, qT, qp, bq, kT, WkB, kph, bk, WvB, vT, vptc, bv);

  fused_attn<<<dim3(256), 1024, 0, stream>>>(qp, kph, vptc, aout);

  transpose_tile<bf16><<<dim3(32, 32, 8), tb, 0, stream>>>(aout, aoutT, 1024, 1024, M1, M1);
  gemm_out<<<512, 256, 0, stream>>>(WoB, aoutT, out, bo);
}